// Round 1
// baseline (102.700 us; speedup 1.0000x reference)
//
#include <hip/hip_runtime.h>

#define KS   13
#define HALF 6
#define TX   64
#define TY   64
#define IN_W (TX + KS - 1)   // 76
#define IN_H (TY + KS - 1)   // 76
#define IMG_H 1024
#define IMG_W 1024

__device__ __forceinline__ int reflect_idx(int i, int n) {
    // single-bounce reflect (offsets <= 6 << n)
    if (i < 0) i = -i;
    if (i >= n) i = 2 * n - 2 - i;
    return i;
}

__global__ __launch_bounds__(256) void gauss_blur_fused(
    const float* __restrict__ x, const float* __restrict__ k2d,
    float* __restrict__ out)
{
    __shared__ float s_in[IN_H][IN_W];  // 76*76*4 = 23104 B
    __shared__ float s_h[IN_H][TX];     // 76*64*4 = 19456 B
    __shared__ float g[KS];

    const int tid = threadIdx.x;
    const int ox  = blockIdx.x * TX;
    const int oy  = blockIdx.y * TY;
    const int img = blockIdx.z;

    const float* xin = x + (size_t)img * IMG_H * IMG_W;
    float*       o   = out + (size_t)img * IMG_H * IMG_W;

    // 1D taps: k2d = outer(g,g) exactly, g[i] = k2d[i][6] / sqrt(k2d[6][6])
    if (tid < KS) {
        float c = k2d[HALF * KS + HALF];
        g[tid] = k2d[tid * KS + HALF] * (1.0f / sqrtf(c));
    }

    // stage input tile (with reflect halo) into LDS
    for (int idx = tid; idx < IN_H * IN_W; idx += 256) {
        int r = idx / IN_W;
        int c = idx - r * IN_W;
        int gr = reflect_idx(oy + r - HALF, IMG_H);
        int gc = reflect_idx(ox + c - HALF, IMG_W);
        s_in[r][c] = xin[gr * IMG_W + gc];
    }
    __syncthreads();

    // horizontal 13-tap pass: s_h[r][c] = blur_x at (oy+r-6, ox+c)
    for (int idx = tid; idx < IN_H * TX; idx += 256) {
        int r = idx >> 6;
        int c = idx & 63;
        float acc = 0.0f;
        #pragma unroll
        for (int j = 0; j < KS; ++j) acc += s_in[r][c + j] * g[j];
        s_h[r][c] = acc;
    }
    __syncthreads();

    // vertical 13-tap pass + coalesced store
    for (int idx = tid; idx < TY * TX; idx += 256) {
        int r = idx >> 6;
        int c = idx & 63;
        float acc = 0.0f;
        #pragma unroll
        for (int i = 0; i < KS; ++i) acc += s_h[r + i][c] * g[i];
        o[(size_t)(oy + r) * IMG_W + (ox + c)] = acc;
    }
}

extern "C" void kernel_launch(void* const* d_in, const int* in_sizes, int n_in,
                              void* d_out, int out_size, void* d_ws, size_t ws_size,
                              hipStream_t stream) {
    const float* x   = (const float*)d_in[0];
    const float* k2d = (const float*)d_in[1];
    float*       out = (float*)d_out;

    dim3 grid(IMG_W / TX, IMG_H / TY, 32);  // 16 x 16 x 32 = 8192 blocks
    gauss_blur_fused<<<grid, 256, 0, stream>>>(x, k2d, out);
}